// Round 8
// baseline (306.618 us; speedup 1.0000x reference)
//
#include <hip/hip_runtime.h>

#define DIM    128
#define NREL   3
#define KS     (NREL*DIM)    // 384
#define NB     16            // nodes per main block; bin = dst>>4
#define LN_EPS 1e-5f
#define PPART  128           // edge partitions (one edge block each)
#define KSLOT  6             // slots per (bin,part) cell
#define PW     (PPART*KSLOT) // 768 ints per bin (9.6 MB total)
#define OVFP   64            // overflow slots per partition
#define CH     256           // main: staged edges per chunk

typedef unsigned int uint;
typedef unsigned char uchar;
typedef float f32x4 __attribute__((ext_vector_type(4)));
typedef short short8 __attribute__((ext_vector_type(8)));

__device__ __forceinline__ unsigned short f2bf(float f) {   // round-to-nearest-even
    union { float f; uint u; } c; c.f = f;
    return (unsigned short)((c.u + 0x7fffu + ((c.u >> 16) & 1u)) >> 16);
}
__device__ __forceinline__ uint packbf(float a, float b) {
    return (uint)f2bf(a) | ((uint)f2bf(b) << 16);
}
__device__ __forceinline__ float blo(uint u) {              // low bf16 -> f32
    union { uint u; float f; } c; c.u = u << 16; return c.f;
}
__device__ __forceinline__ float bhi(uint u) {              // high bf16 -> f32
    union { uint u; float f; } c; c.u = u & 0xffff0000u; return c.f;
}
// Index element i from an "int" input that may really be int64 (i64 flag)
__device__ __forceinline__ int ldidx(const int* p, size_t i, int i64) {
    return i64 ? p[2*i] : p[i];
}
// 16B-slot offset of A-frag holding A[m][k..k+7] (k%8==0), 16-row tile,
// mfma_f32_16x16x32_bf16: slot = (k>>5)*64 + ((k>>3)&3)*16 + m
__device__ __forceinline__ int fo(int m, int k) {
    return ((k >> 5) << 6) + ((((k >> 3) & 3)) << 4) + m;
}
// Bank swizzle: XOR bits>=4 into bits 0-2. Bijective; balances write banks
// while leaving the MFMA read distribution at the free 2-lanes/bank.
__device__ __forceinline__ int SW(int s) { return s ^ ((s >> 4) & 7); }

// Per-block int64 probe: int64 storage => ~half of first 256 words are zero.
__device__ __forceinline__ void block_probe(const int* __restrict__ ei, int t, int* s_i64) {
    if (t < 64) {
        int z = 0;
        #pragma unroll
        for (int i = 0; i < 4; i++) z += (ei[t*4 + i] == 0) ? 1 : 0;
        #pragma unroll
        for (int off = 1; off < 64; off <<= 1) z += __shfl_xor(z, off);
        if (t == 0) *s_i64 = (z > 64) ? 1 : 0;
    }
}

// B-pack: Wbig (fp32) -> bf16 B-fragment order, 8192 uint4.
// Wbig[k][n]: k<384 -> relation_weights[k*128+n]; k>=384 -> lin_w[n*128+(k-384)]
__device__ __forceinline__ void bpack_work(int idx, const float* __restrict__ relw,
                                           const float* __restrict__ linw,
                                           unsigned short* __restrict__ Bpack) {
    if (idx < 8192) {
        int lane = idx & 63, kk = (idx >> 6) & 15, tile = idx >> 10;
        int q = lane >> 4, n = tile * 16 + (lane & 15);
        uint vv[4];
        #pragma unroll
        for (int jp = 0; jp < 4; jp++) {
            int k0 = kk * 32 + q * 8 + jp * 2;
            float v0 = (k0     < KS) ? relw[(size_t)k0*DIM + n]
                                     : linw[(size_t)n*DIM + (k0 - KS)];
            float v1 = (k0 + 1 < KS) ? relw[(size_t)(k0+1)*DIM + n]
                                     : linw[(size_t)n*DIM + (k0 + 1 - KS)];
            vv[jp] = packbf(v0, v1);
        }
        uint4 v; v.x = vv[0]; v.y = vv[1]; v.z = vv[2]; v.w = vv[3];
        ((uint4*)Bpack)[idx] = v;
    }
}

// ---------------------------------------------------------------------------
// edge_kernel: 128 blocks x 512 thr; partition b owns edges [b*Ee,(b+1)*Ee).
// LDS hist over NBIN bins; atomic return = rank in (bin,b) cell;
// rank<KSLOT -> binbuf[bin*PW + b*KSLOT + rank] = tag (FINAL position, no
// scan/fill). rank>=KSLOT -> per-partition overflow list (expected ~400
// edges total at lambda=1.5; list keeps correctness).
// tag = src | (dst&15)<<20 | rel<<24   (src < 2^20)
// ---------------------------------------------------------------------------
__global__ __launch_bounds__(512)
void edge_kernel(const int* __restrict__ ei, const int* __restrict__ et,
                 int E, int Ee, int NBIN,
                 uchar* __restrict__ cnt, int* __restrict__ binbuf,
                 int* __restrict__ ovf_cnt, int2* __restrict__ ovf)
{
    extern __shared__ int lhist[];          // NBIN ints
    __shared__ int s_i64;
    __shared__ int s_ovf;
    const int b = blockIdx.x, t = threadIdx.x;

    block_probe(ei, t, &s_i64);
    if (t == 0) s_ovf = 0;
    for (int i = t; i < NBIN; i += 512) lhist[i] = 0;
    __syncthreads();
    const int i64 = s_i64;
    const int e0 = b * Ee;
    const int e1 = min(E, e0 + Ee);
    for (int e = e0 + t; e < e1; e += 512) {
        int s = ldidx(ei, (size_t)e, i64);
        int d = ldidx(ei, (size_t)E + e, i64);
        int r = ldidx(et, (size_t)e, i64);
        int bin = d >> 4;
        int tag = s | ((d & 15) << 20) | (r << 24);
        int lr = atomicAdd(&lhist[bin], 1);
        if (lr < KSLOT) {
            binbuf[bin * PW + b * KSLOT + lr] = tag;
        } else {
            int oi = atomicAdd(&s_ovf, 1);
            if (oi < OVFP) ovf[b * OVFP + oi] = make_int2(tag, bin);
        }
    }
    __syncthreads();
    for (int i = t; i < NBIN; i += 512)
        cnt[i * PPART + b] = (uchar)min(lhist[i], KSLOT);
    if (t == 0) ovf_cnt[b] = min(s_ovf, OVFP);
}

// ---------------------------------------------------------------------------
// convert_kernel: pure streaming. x->bf16 (one 32B-load/16B-store per thread)
// + B-pack. No LDS -> full occupancy.
// ---------------------------------------------------------------------------
__global__ __launch_bounds__(256)
void convert_kernel(const float* __restrict__ x, int N,
                    const float* __restrict__ relw, const float* __restrict__ linw,
                    unsigned short* __restrict__ Bpack, unsigned short* __restrict__ xbf)
{
    const int tid  = blockIdx.x * 256 + threadIdx.x;
    const int nthr = gridDim.x * 256;
    const float4* x4 = (const float4*)x;
    const int items = N * (DIM / 8);        // 8 floats -> 4 packed uints
    for (int i = tid; i < items; i += nthr) {
        float4 a = x4[i*2], bb = x4[i*2 + 1];
        uint4 v;
        v.x = packbf(a.x, a.y); v.y = packbf(a.z, a.w);
        v.z = packbf(bb.x, bb.y); v.w = packbf(bb.z, bb.w);
        ((uint4*)xbf)[i] = v;
    }
    bpack_work(tid, relw, linw, Bpack);
}

// ---------------------------------------------------------------------------
// main: block bb owns bin bb (nodes [bb*16, bb*16+16)). 2-wave hierarchical
// scan of the 128 cell counts; per <=CH-slot group: parallel slot->cell map
// (1 cell/thread), tags staged to registers, 48-key (node,rel) compaction,
// 4-way-unrolled gather, then MFMA + LN + epilogue.
// Fast path skips the group-boundary walk when the whole bin fits one chunk.
// ---------------------------------------------------------------------------
__global__ __launch_bounds__(256)
void main_kernel(const unsigned short* __restrict__ xbf,
                 const uchar* __restrict__ cnt,
                 const int* __restrict__ binbuf,
                 const int* __restrict__ ovf_cnt, const int2* __restrict__ ovf,
                 const unsigned short* __restrict__ Bpack,
                 const float* __restrict__ linb,
                 const float* __restrict__ gamma,
                 const float* __restrict__ beta,
                 float* __restrict__ out, int N)
{
    __shared__ uint4 Af[1024];              // 16 KiB: A-frags; staging aliases
    __shared__ int s_cnt[48];
    __shared__ int s_off[49];
    __shared__ int s_cur[48];
    __shared__ int s_coff[PPART + 1];
    __shared__ int s_ws[4];
    __shared__ int s_n;
    __shared__ int s_ovfL;
    __shared__ float s_mu[NB], s_rs[NB];

    int* s_tag = (int*)Af;                  // [0..255]   (overflow staging)
    int* s_cmp = (int*)Af + 256;            // [256..511] (compacted srcs)
    int* s_map = (int*)Af + 512;            // [512..767] (slot -> cell)

    const int t  = threadIdx.x;             // 0..255
    const int bb = blockIdx.x;
    const int n0 = bb * NB;
    const int m  = t >> 4;                  // node-local 0..15
    const int c  = t & 15;                  // owns dims [8c, 8c+8)
    const int n  = n0 + m;
    const int lane = t & 63;
    const int wv   = t >> 6;

    const uint4* xh = (const uint4*)xbf;    // 16 uint4 per bf16 row

    float a0[8], a1[8], a2[8];
    #pragma unroll
    for (int i = 0; i < 8; i++) { a0[i] = 0.f; a1[i] = 0.f; a2[i] = 0.f; }
    int deg = 0;
    uint4 res = {0,0,0,0};
    if (n < N) res = xh[(size_t)n*16 + c];  // residual (already bf16-packed)

    // ---- cell offsets: 2-wave hierarchical inclusive scan over PPART counts
    if (t == 0) s_ovfL = 0;
    int vsc = 0;
    if (t < PPART) vsc = (int)cnt[(size_t)bb * PPART + t];
    {
        #pragma unroll
        for (int off = 1; off < 64; off <<= 1) {
            int u = __shfl_up(vsc, off);
            if (lane >= off) vsc += u;
        }
        if (t < PPART && lane == 63) s_ws[wv] = vsc;
    }
    __syncthreads();
    if (t < PPART) {
        int wpre = 0;
        #pragma unroll
        for (int k = 0; k < (PPART/64) - 1; k++) if (k < wv) wpre += s_ws[k];
        s_coff[t + 1] = vsc + wpre;
    }
    if (t == 0) s_coff[0] = 0;
    {                                       // concurrent: total overflow count
        int ov = (t < PPART) ? ovf_cnt[t] : 0;
        #pragma unroll
        for (int off = 1; off < 64; off <<= 1) ov += __shfl_xor(ov, off);
        if (lane == 0 && t < PPART) atomicAdd(&s_ovfL, ov);
    }
    __syncthreads();

    // phases 3-5 shared by main loop and overflow chunk:
    // assumes: s_cnt counted, `key`/`tg` registers set for t<nc, sync done.
    #define FINISH_CHUNK(NC) { \
        const int nc_ = (NC); \
        if (t < 64) { \
            int cv_ = (t < 48) ? s_cnt[t] : 0; \
            int v_ = cv_; \
            _Pragma("unroll") \
            for (int off = 1; off < 64; off <<= 1) { \
                int u_ = __shfl_up(v_, off); \
                if (t >= off) v_ += u_; \
            } \
            if (t < 48) { s_off[t + 1] = v_; s_cur[t] = v_ - cv_; } \
            if (t == 0) s_off[0] = 0; \
        } \
        __syncthreads(); \
        if (t < nc_) { \
            int pos_ = atomicAdd(&s_cur[key], 1); \
            s_cmp[pos_] = tg & 0xFFFFF; \
        } \
        __syncthreads(); \
        deg += s_off[m*3 + 3] - s_off[m*3]; \
        { \
            int p_ = s_off[m*3 + 0], pe_ = s_off[m*3 + 1]; \
            GATH(a0) \
            p_ = s_off[m*3 + 1]; pe_ = s_off[m*3 + 2]; \
            GATH(a1) \
            p_ = s_off[m*3 + 2]; pe_ = s_off[m*3 + 3]; \
            GATH(a2) \
        } \
        __syncthreads(); }

    #define GATH(ACC) \
        for (; p_ + 3 < pe_; p_ += 4) { \
            int s0 = s_cmp[p_],   s1 = s_cmp[p_+1]; \
            int s2 = s_cmp[p_+2], s3 = s_cmp[p_+3]; \
            uint4 g0 = xh[(size_t)s0*16 + c], g1 = xh[(size_t)s1*16 + c]; \
            uint4 g2 = xh[(size_t)s2*16 + c], g3 = xh[(size_t)s3*16 + c]; \
            ACC[0] += blo(g0.x)+blo(g1.x)+blo(g2.x)+blo(g3.x); \
            ACC[1] += bhi(g0.x)+bhi(g1.x)+bhi(g2.x)+bhi(g3.x); \
            ACC[2] += blo(g0.y)+blo(g1.y)+blo(g2.y)+blo(g3.y); \
            ACC[3] += bhi(g0.y)+bhi(g1.y)+bhi(g2.y)+bhi(g3.y); \
            ACC[4] += blo(g0.z)+blo(g1.z)+blo(g2.z)+blo(g3.z); \
            ACC[5] += bhi(g0.z)+bhi(g1.z)+bhi(g2.z)+bhi(g3.z); \
            ACC[6] += blo(g0.w)+blo(g1.w)+blo(g2.w)+blo(g3.w); \
            ACC[7] += bhi(g0.w)+bhi(g1.w)+bhi(g2.w)+bhi(g3.w); \
        } \
        for (; p_ < pe_; ++p_) { \
            int s0 = s_cmp[p_]; \
            uint4 g0 = xh[(size_t)s0*16 + c]; \
            ACC[0] += blo(g0.x); ACC[1] += bhi(g0.x); \
            ACC[2] += blo(g0.y); ACC[3] += bhi(g0.y); \
            ACC[4] += blo(g0.z); ACC[5] += bhi(g0.z); \
            ACC[6] += blo(g0.w); ACC[7] += bhi(g0.w); \
        }

    // ---- slotted cells, processed in groups with total <= CH ----
    int g0 = 0;
    while (g0 < PPART) {
        const int base0 = s_coff[g0];
        int gend;
        if (s_coff[PPART] - base0 <= CH) {
            gend = PPART;                   // common case: whole bin fits
        } else {
            gend = g0;
            while (gend < PPART && s_coff[gend + 1] - base0 <= CH) ++gend;
        }
        const int nc = s_coff[gend] - base0;
        // phase 1: zero key-counts + parallel slot->cell map (1 cell/thread)
        if (t < 48) s_cnt[t] = 0;
        for (int cell = g0 + t; cell < gend; cell += 256) {
            int lo = s_coff[cell] - base0, hi = s_coff[cell + 1] - base0;
            for (int s2 = lo; s2 < hi; ++s2) s_map[s2] = cell;
        }
        __syncthreads();
        // phase 2: stage tag to register + key count
        int key = -1, tg = 0;
        if (t < nc) {
            int cell = s_map[t];
            int slot = t - (s_coff[cell] - base0);
            tg = binbuf[(size_t)bb * PW + cell * KSLOT + slot];
            key = (((tg >> 20) & 15) * 3) + ((tg >> 24) & 3);
            atomicAdd(&s_cnt[key], 1);
        }
        __syncthreads();
        FINISH_CHUNK(nc)
        g0 = gend;
    }

    // ---- overflow lists (normally ~400 edges globally) ----
    if (s_ovfL > 0) {
        if (t == 0) s_n = 0;
        if (t < 48) s_cnt[t] = 0;
        __syncthreads();
        for (int p = 0; p < PPART; p++) {
            int L = ovf_cnt[p];
            for (int i = t; i < L; i += 256) {
                int2 o = ovf[p * OVFP + i];
                if (o.y == bb) {
                    int pos = atomicAdd(&s_n, 1);
                    if (pos < CH) s_tag[pos] = o.x;
                }
            }
        }
        __syncthreads();
        int nc = min(s_n, CH);
        int key = -1, tg = 0;
        if (t < nc) {
            tg = s_tag[t];
            key = (((tg >> 20) & 15) * 3) + ((tg >> 24) & 3);
            atomicAdd(&s_cnt[key], 1);
        }
        __syncthreads();
        FINISH_CHUNK(nc)
    }
    #undef GATH
    #undef FINISH_CHUNK

    {   // pack A-frags (messages scaled by 1/deg, plus residual)
        float inv = 1.0f / fmaxf((float)deg, 1.0f);
        uint4 w0;
        w0.x = packbf(a0[0]*inv, a0[1]*inv); w0.y = packbf(a0[2]*inv, a0[3]*inv);
        w0.z = packbf(a0[4]*inv, a0[5]*inv); w0.w = packbf(a0[6]*inv, a0[7]*inv);
        Af[SW(fo(m, 0*DIM + 8*c))] = w0;
        w0.x = packbf(a1[0]*inv, a1[1]*inv); w0.y = packbf(a1[2]*inv, a1[3]*inv);
        w0.z = packbf(a1[4]*inv, a1[5]*inv); w0.w = packbf(a1[6]*inv, a1[7]*inv);
        Af[SW(fo(m, 1*DIM + 8*c))] = w0;
        w0.x = packbf(a2[0]*inv, a2[1]*inv); w0.y = packbf(a2[2]*inv, a2[3]*inv);
        w0.z = packbf(a2[4]*inv, a2[5]*inv); w0.w = packbf(a2[6]*inv, a2[7]*inv);
        Af[SW(fo(m, 2*DIM + 8*c))] = w0;
        Af[SW(fo(m, KS + 8*c))] = res;
    }
    __syncthreads();

    // ---------------- MFMA GEMM: 4 waves x 2 output tiles ----------------
    const int w    = wv;                    // 0..3 (wave)
    const int mm   = lane & 15;
    const int q    = lane >> 4;
    f32x4 acc0 = {0,0,0,0}, acc1 = {0,0,0,0};
    {
        const short8* Aq = (const short8*)Af;
        const short8* Bq = (const short8*)Bpack;
        #pragma unroll
        for (int kk = 0; kk < 16; kk++) {
            short8 a  = Aq[SW(kk*64 + lane)];
            short8 b0 = Bq[((w*2 + 0)*16 + kk)*64 + lane];
            short8 b1 = Bq[((w*2 + 1)*16 + kk)*64 + lane];
            acc0 = __builtin_amdgcn_mfma_f32_16x16x32_bf16(a, b0, acc0, 0, 0, 0);
            acc1 = __builtin_amdgcn_mfma_f32_16x16x32_bf16(a, b1, acc1, 0, 0, 0);
        }
    }
    __syncthreads();                        // all A reads done; reuse as H

    float* H = (float*)Af;                  // H[16][132] = 8448 B < 16 KiB
    {
        int rb = q * 4;
        #pragma unroll
        for (int nt = 0; nt < 2; nt++) {
            int d = (w*2 + nt)*16 + mm;
            float lb = linb[d];
            f32x4 a = (nt == 0) ? acc0 : acc1;
            #pragma unroll
            for (int i = 0; i < 4; i++)
                H[(rb + i)*132 + d] = a[i] + lb;
        }
    }
    __syncthreads();

    // ---------------- LayerNorm stats (16 lanes per row) ----------------
    {
        int j = t >> 4, p = t & 15;
        float s1 = 0.f, s2 = 0.f;
        const float* hr = &H[j*132 + p*8];
        #pragma unroll
        for (int i = 0; i < 8; i++) { float v = hr[i]; s1 += v; s2 += v*v; }
        #pragma unroll
        for (int off = 1; off < 16; off <<= 1) {
            s1 += __shfl_xor(s1, off);
            s2 += __shfl_xor(s2, off);
        }
        if (p == 0) {
            float mu  = s1 * (1.0f/DIM);
            float var = s2 * (1.0f/DIM) - mu*mu;
            s_mu[j] = mu;
            s_rs[j] = rsqrtf(var + LN_EPS);
        }
    }
    __syncthreads();

    // ---------------- output (fp32), 2 half-blocks x 8 rows ----------------
    {
        int d  = t & 127;
        int jb = (t >> 7) * 8;
        float g = gamma[d];
        float b = beta[d];
        #pragma unroll
        for (int jj = 0; jj < 8; jj++) {
            int j = jb + jj;
            int nn = n0 + j;
            if (nn < N) {
                float hv = H[j*132 + d];
                out[(size_t)nn*DIM + d] = g * (hv - s_mu[j]) * s_rs[j] + b;
            }
        }
    }
}

extern "C" void kernel_launch(void* const* d_in, const int* in_sizes, int n_in,
                              void* d_out, int out_size, void* d_ws, size_t ws_size,
                              hipStream_t stream)
{
    const float* x   = (const float*)d_in[0];
    const int*   ei  = (const int*)d_in[1];
    const int*   et  = (const int*)d_in[2];
    const float* rw  = (const float*)d_in[3];
    const float* lw  = (const float*)d_in[4];
    const float* lb  = (const float*)d_in[5];
    const float* lg  = (const float*)d_in[6];
    const float* lbe = (const float*)d_in[7];

    const int N    = in_sizes[0] / DIM;
    const int E    = in_sizes[2];
    const int NBIN = (N + NB - 1) / NB;            // 3125 for N=50000
    const int Ee   = (E + PPART - 1) / PPART;      // 4688

    // ws layout (~23.0 MB): ovf_cnt[128] | ovf | cnt | binbuf | Bpack | xbf
    char* wp = (char*)d_ws;
    int*  ovf_cnt = (int*)wp;             wp += 512;
    int2* ovf     = (int2*)wp;            wp += (size_t)PPART * OVFP * 8;       // 65 KB
    uchar* cnt    = (uchar*)wp;           wp += ((size_t)NBIN * PPART + 63) & ~(size_t)63;
    int*  binbuf  = (int*)wp;             wp += (size_t)NBIN * PW * 4;          // 9.6 MB
    unsigned short* Bpack = (unsigned short*)wp;   wp += 512 * 128 * 2;         // 128 KB
    unsigned short* xbf   = (unsigned short*)wp;   wp += (size_t)N * DIM * 2;   // 12.8 MB
    (void)ws_size;

    edge_kernel<<<PPART, 512, (size_t)NBIN * 4, stream>>>(ei, et, E, Ee, NBIN,
                                                          cnt, binbuf, ovf_cnt, ovf);
    convert_kernel<<<(N * (DIM/8) + 255) / 256, 256, 0, stream>>>(x, N, rw, lw,
                                                                  Bpack, xbf);
    main_kernel<<<NBIN, 256, 0, stream>>>(xbf, cnt, binbuf, ovf_cnt, ovf, Bpack,
                                          lb, lg, lbe, (float*)d_out, N);
}

// Round 10
// 178.289 us; speedup vs baseline: 1.7198x; 1.7198x over previous
//
#include <hip/hip_runtime.h>

#define DIM    128
#define NREL   3
#define KS     (NREL*DIM)    // 384
#define NB     16            // nodes per main block; bin = dst>>4
#define LN_EPS 1e-5f
#define PPART  96            // edge partitions (one edge block each)
#define KSLOT  8             // slots per (bin,part) cell
#define PW     (PPART*KSLOT) // 768 ints per bin (9.6 MB total, proven size)
#define OVFCAP 4096          // single global overflow list (expected ~84 used)
#define CH     256           // main: staged edges per chunk

typedef unsigned int uint;
typedef unsigned char uchar;
typedef float f32x4 __attribute__((ext_vector_type(4)));
typedef short short8 __attribute__((ext_vector_type(8)));

__device__ __forceinline__ unsigned short f2bf(float f) {   // round-to-nearest-even
    union { float f; uint u; } c; c.f = f;
    return (unsigned short)((c.u + 0x7fffu + ((c.u >> 16) & 1u)) >> 16);
}
__device__ __forceinline__ uint packbf(float a, float b) {
    return (uint)f2bf(a) | ((uint)f2bf(b) << 16);
}
__device__ __forceinline__ float blo(uint u) {              // low bf16 -> f32
    union { uint u; float f; } c; c.u = u << 16; return c.f;
}
__device__ __forceinline__ float bhi(uint u) {              // high bf16 -> f32
    union { uint u; float f; } c; c.u = u & 0xffff0000u; return c.f;
}
// Index element i from an "int" input that may really be int64 (i64 flag)
__device__ __forceinline__ int ldidx(const int* p, size_t i, int i64) {
    return i64 ? p[2*i] : p[i];
}
// 16B-slot offset of A-frag holding A[m][k..k+7] (k%8==0), 16-row tile,
// mfma_f32_16x16x32_bf16: slot = (k>>5)*64 + ((k>>3)&3)*16 + m
__device__ __forceinline__ int fo(int m, int k) {
    return ((k >> 5) << 6) + ((((k >> 3) & 3)) << 4) + m;
}
// Bank swizzle: XOR bits>=4 into bits 0-2. Bijective; balances write banks
// while leaving the MFMA read distribution at the free 2-lanes/bank.
__device__ __forceinline__ int SW(int s) { return s ^ ((s >> 4) & 7); }

// Per-block int64 probe: int64 storage => ~half of first 256 words are zero.
__device__ __forceinline__ void block_probe(const int* __restrict__ ei, int t, int* s_i64) {
    if (t < 64) {
        int z = 0;
        #pragma unroll
        for (int i = 0; i < 4; i++) z += (ei[t*4 + i] == 0) ? 1 : 0;
        #pragma unroll
        for (int off = 1; off < 64; off <<= 1) z += __shfl_xor(z, off);
        if (t == 0) *s_i64 = (z > 64) ? 1 : 0;
    }
}

// B-pack: Wbig (fp32) -> bf16 B-fragment order, 8192 uint4.
// Wbig[k][n]: k<384 -> relation_weights[k*128+n]; k>=384 -> lin_w[n*128+(k-384)]
__device__ __forceinline__ void bpack_work(int idx, const float* __restrict__ relw,
                                           const float* __restrict__ linw,
                                           unsigned short* __restrict__ Bpack) {
    if (idx < 8192) {
        int lane = idx & 63, kk = (idx >> 6) & 15, tile = idx >> 10;
        int q = lane >> 4, n = tile * 16 + (lane & 15);
        uint vv[4];
        #pragma unroll
        for (int jp = 0; jp < 4; jp++) {
            int k0 = kk * 32 + q * 8 + jp * 2;
            float v0 = (k0     < KS) ? relw[(size_t)k0*DIM + n]
                                     : linw[(size_t)n*DIM + (k0 - KS)];
            float v1 = (k0 + 1 < KS) ? relw[(size_t)(k0+1)*DIM + n]
                                     : linw[(size_t)n*DIM + (k0 + 1 - KS)];
            vv[jp] = packbf(v0, v1);
        }
        uint4 v; v.x = vv[0]; v.y = vv[1]; v.z = vv[2]; v.w = vv[3];
        ((uint4*)Bpack)[idx] = v;
    }
}

// ---------------------------------------------------------------------------
// convert_kernel (runs FIRST, stream-serial): x->bf16 (one 32B-load/16B-store
// per thread, grid-stride) + B-pack + zero the overflow counter/flags used by
// edge_kernel.
// ---------------------------------------------------------------------------
__global__ __launch_bounds__(256)
void convert_kernel(const float* __restrict__ x, int N, int NBIN,
                    const float* __restrict__ relw, const float* __restrict__ linw,
                    unsigned short* __restrict__ Bpack, unsigned short* __restrict__ xbf,
                    int* __restrict__ ovfn, uchar* __restrict__ ovfb)
{
    const int tid  = blockIdx.x * 256 + threadIdx.x;
    const int nthr = gridDim.x * 256;
    if (tid == 0) *ovfn = 0;
    for (int i = tid; i < NBIN; i += nthr) ovfb[i] = 0;

    const float4* x4 = (const float4*)x;
    const int items = N * (DIM / 8);        // 8 floats -> 4 packed uints
    for (int i = tid; i < items; i += nthr) {
        float4 a = x4[i*2], bb = x4[i*2 + 1];
        uint4 v;
        v.x = packbf(a.x, a.y); v.y = packbf(a.z, a.w);
        v.z = packbf(bb.x, bb.y); v.w = packbf(bb.z, bb.w);
        ((uint4*)xbf)[i] = v;
    }
    bpack_work(tid, relw, linw, Bpack);
}

// ---------------------------------------------------------------------------
// edge_kernel: 96 blocks x 512 thr; partition b owns edges [b*Ee,(b+1)*Ee).
// LDS hist over NBIN bins; atomic return = rank in (bin,b) cell;
// rank<KSLOT -> binbuf[bin*PW + b*KSLOT + rank] = tag (FINAL position).
// rank>=KSLOT (expected ~84 edges total at lambda=2) -> single global list
// via global atomic (few ops) + per-bin flag so main gates the scan.
// tag = src | (dst&15)<<20 | rel<<24   (src < 2^20)
// ---------------------------------------------------------------------------
__global__ __launch_bounds__(512)
void edge_kernel(const int* __restrict__ ei, const int* __restrict__ et,
                 int E, int Ee, int NBIN,
                 uchar* __restrict__ cnt, int* __restrict__ binbuf,
                 int* __restrict__ ovfn, uchar* __restrict__ ovfb,
                 int2* __restrict__ ovf)
{
    extern __shared__ int lhist[];          // NBIN ints
    __shared__ int s_i64;
    const int b = blockIdx.x, t = threadIdx.x;

    block_probe(ei, t, &s_i64);
    for (int i = t; i < NBIN; i += 512) lhist[i] = 0;
    __syncthreads();
    const int i64 = s_i64;
    const int e0 = b * Ee;
    const int e1 = min(E, e0 + Ee);
    for (int e = e0 + t; e < e1; e += 512) {
        int s = ldidx(ei, (size_t)e, i64);
        int d = ldidx(ei, (size_t)E + e, i64);
        int r = ldidx(et, (size_t)e, i64);
        int bin = d >> 4;
        int tag = s | ((d & 15) << 20) | (r << 24);
        int lr = atomicAdd(&lhist[bin], 1);
        if (lr < KSLOT) {
            binbuf[bin * PW + b * KSLOT + lr] = tag;
        } else {
            int oi = atomicAdd(ovfn, 1);
            if (oi < OVFCAP) { ovf[oi] = make_int2(tag, bin); ovfb[bin] = 1; }
        }
    }
    __syncthreads();
    for (int i = t; i < NBIN; i += 512)
        cnt[i * PPART + b] = (uchar)min(lhist[i], KSLOT);
}

// ---------------------------------------------------------------------------
// main: block bb owns bin bb (nodes [bb*16, bb*16+16)). Explicit 2-wave
// shuffle scan of the 96 cell counts; per <=CH-slot group: parallel
// slot->cell map, register-staged tags, 48-key (node,rel) compaction,
// 4-way-unrolled gather; overflow handled ONLY when ovfb[bb] set (~80/3125
// blocks, one pass over a ~84-entry list). Then MFMA + LN + epilogue.
// LDS ~19.6KB -> 8 blocks/CU (the R5-proven occupancy point).
// ---------------------------------------------------------------------------
__global__ __launch_bounds__(256)
void main_kernel(const unsigned short* __restrict__ xbf,
                 const uchar* __restrict__ cnt,
                 const int* __restrict__ binbuf,
                 const int* __restrict__ ovfn, const uchar* __restrict__ ovfb,
                 const int2* __restrict__ ovf,
                 const unsigned short* __restrict__ Bpack,
                 const float* __restrict__ linb,
                 const float* __restrict__ gamma,
                 const float* __restrict__ beta,
                 float* __restrict__ out, int N)
{
    __shared__ uint4 Af[1024];              // 16 KiB: A-frags, reused as H[16][132]
    __shared__ int s_cmp[CH];               // compacted srcs, (node,rel)-segmented
    __shared__ int s_map[CH];               // slot->cell map; reused as ovf staging
    __shared__ int s_cnt[48];
    __shared__ int s_off[49];
    __shared__ int s_cur[48];
    __shared__ int s_coff[PPART + 1];
    __shared__ int s_ws0;
    __shared__ int s_n;
    __shared__ int s_flag;
    __shared__ float s_mu[NB], s_rs[NB];

    const int t  = threadIdx.x;             // 0..255
    const int bb = blockIdx.x;
    const int n0 = bb * NB;
    const int m  = t >> 4;                  // node-local 0..15
    const int c  = t & 15;                  // owns dims [8c, 8c+8)
    const int n  = n0 + m;
    const int lane = t & 63;

    const uint4* xh = (const uint4*)xbf;    // 16 uint4 per bf16 row

    float a0[8], a1[8], a2[8];
    #pragma unroll
    for (int i = 0; i < 8; i++) { a0[i] = 0.f; a1[i] = 0.f; a2[i] = 0.f; }
    int deg = 0;
    uint4 res = {0,0,0,0};
    if (n < N) res = xh[(size_t)n*16 + c];  // residual (already bf16-packed)
    if (t == 0) s_flag = (int)ovfb[bb];

    // ---- cell offsets: explicit 2-wave inclusive scan over 96 counts ----
    int vsc = 0;
    if (t < PPART) vsc = (int)cnt[(size_t)bb * PPART + t];
    #pragma unroll
    for (int off = 1; off < 64; off <<= 1) {
        int u = __shfl_up(vsc, off);
        if (lane >= off) vsc += u;
    }
    if (t == 63) s_ws0 = vsc;               // wave-0 total
    __syncthreads();
    if (t < PPART) s_coff[t + 1] = vsc + ((t >= 64) ? s_ws0 : 0);
    if (t == 0) s_coff[0] = 0;
    __syncthreads();

    // phases 3-5 shared by main loop and overflow chunk:
    // assumes: s_cnt counted, `key`/`tg` registers set for t<nc, sync done.
    #define FINISH_CHUNK(NC) { \
        const int nc_ = (NC); \
        if (t < 64) { \
            int cv_ = (t < 48) ? s_cnt[t] : 0; \
            int v_ = cv_; \
            _Pragma("unroll") \
            for (int off = 1; off < 64; off <<= 1) { \
                int u_ = __shfl_up(v_, off); \
                if (t >= off) v_ += u_; \
            } \
            if (t < 48) { s_off[t + 1] = v_; s_cur[t] = v_ - cv_; } \
            if (t == 0) s_off[0] = 0; \
        } \
        __syncthreads(); \
        if (t < nc_) { \
            int pos_ = atomicAdd(&s_cur[key], 1); \
            s_cmp[pos_] = tg & 0xFFFFF; \
        } \
        __syncthreads(); \
        deg += s_off[m*3 + 3] - s_off[m*3]; \
        { \
            int p_ = s_off[m*3 + 0], pe_ = s_off[m*3 + 1]; \
            GATH(a0) \
            p_ = s_off[m*3 + 1]; pe_ = s_off[m*3 + 2]; \
            GATH(a1) \
            p_ = s_off[m*3 + 2]; pe_ = s_off[m*3 + 3]; \
            GATH(a2) \
        } \
        __syncthreads(); }

    #define GATH(ACC) \
        for (; p_ + 3 < pe_; p_ += 4) { \
            int s0 = s_cmp[p_],   s1 = s_cmp[p_+1]; \
            int s2 = s_cmp[p_+2], s3 = s_cmp[p_+3]; \
            uint4 g0 = xh[(size_t)s0*16 + c], g1 = xh[(size_t)s1*16 + c]; \
            uint4 g2 = xh[(size_t)s2*16 + c], g3 = xh[(size_t)s3*16 + c]; \
            ACC[0] += blo(g0.x)+blo(g1.x)+blo(g2.x)+blo(g3.x); \
            ACC[1] += bhi(g0.x)+bhi(g1.x)+bhi(g2.x)+bhi(g3.x); \
            ACC[2] += blo(g0.y)+blo(g1.y)+blo(g2.y)+blo(g3.y); \
            ACC[3] += bhi(g0.y)+bhi(g1.y)+bhi(g2.y)+bhi(g3.y); \
            ACC[4] += blo(g0.z)+blo(g1.z)+blo(g2.z)+blo(g3.z); \
            ACC[5] += bhi(g0.z)+bhi(g1.z)+bhi(g2.z)+bhi(g3.z); \
            ACC[6] += blo(g0.w)+blo(g1.w)+blo(g2.w)+blo(g3.w); \
            ACC[7] += bhi(g0.w)+bhi(g1.w)+bhi(g2.w)+bhi(g3.w); \
        } \
        for (; p_ < pe_; ++p_) { \
            int s0 = s_cmp[p_]; \
            uint4 g0 = xh[(size_t)s0*16 + c]; \
            ACC[0] += blo(g0.x); ACC[1] += bhi(g0.x); \
            ACC[2] += blo(g0.y); ACC[3] += bhi(g0.y); \
            ACC[4] += blo(g0.z); ACC[5] += bhi(g0.z); \
            ACC[6] += blo(g0.w); ACC[7] += bhi(g0.w); \
        }

    // ---- slotted cells, processed in groups with total <= CH ----
    int g0 = 0;
    while (g0 < PPART) {
        const int base0 = s_coff[g0];
        int gend;
        if (s_coff[PPART] - base0 <= CH) {
            gend = PPART;                   // common case: whole bin fits
        } else {
            gend = g0;
            while (gend < PPART && s_coff[gend + 1] - base0 <= CH) ++gend;
        }
        const int nc = s_coff[gend] - base0;
        // phase 1: zero key-counts + parallel slot->cell map (1 cell/thread)
        if (t < 48) s_cnt[t] = 0;
        for (int cell = g0 + t; cell < gend; cell += 256) {
            int lo = s_coff[cell] - base0, hi = s_coff[cell + 1] - base0;
            for (int s2 = lo; s2 < hi; ++s2) s_map[s2] = cell;
        }
        __syncthreads();
        // phase 2: stage tag to register + key count
        int key = -1, tg = 0;
        if (t < nc) {
            int cell = s_map[t];
            int slot = t - (s_coff[cell] - base0);
            tg = binbuf[(size_t)bb * PW + cell * KSLOT + slot];
            key = (((tg >> 20) & 15) * 3) + ((tg >> 24) & 3);
            atomicAdd(&s_cnt[key], 1);
        }
        __syncthreads();
        FINISH_CHUNK(nc)
        g0 = gend;
    }

    // ---- overflow (gated: ~80 of 3125 blocks; one pass over ~84 entries) ----
    if (s_flag) {
        int L = min(ovfn[0], OVFCAP);
        if (t == 0) s_n = 0;
        if (t < 48) s_cnt[t] = 0;
        __syncthreads();
        for (int i = t; i < L; i += 256) {
            int2 o = ovf[i];
            if (o.y == bb) {
                int pos = atomicAdd(&s_n, 1);
                if (pos < CH) s_map[pos] = o.x;
            }
        }
        __syncthreads();
        int nc = min(s_n, CH);
        int key = -1, tg = 0;
        if (t < nc) {
            tg = s_map[t];
            key = (((tg >> 20) & 15) * 3) + ((tg >> 24) & 3);
            atomicAdd(&s_cnt[key], 1);
        }
        __syncthreads();
        FINISH_CHUNK(nc)
    }
    #undef GATH
    #undef FINISH_CHUNK

    {   // pack A-frags (messages scaled by 1/deg, plus residual)
        float inv = 1.0f / fmaxf((float)deg, 1.0f);
        uint4 w0;
        w0.x = packbf(a0[0]*inv, a0[1]*inv); w0.y = packbf(a0[2]*inv, a0[3]*inv);
        w0.z = packbf(a0[4]*inv, a0[5]*inv); w0.w = packbf(a0[6]*inv, a0[7]*inv);
        Af[SW(fo(m, 0*DIM + 8*c))] = w0;
        w0.x = packbf(a1[0]*inv, a1[1]*inv); w0.y = packbf(a1[2]*inv, a1[3]*inv);
        w0.z = packbf(a1[4]*inv, a1[5]*inv); w0.w = packbf(a1[6]*inv, a1[7]*inv);
        Af[SW(fo(m, 1*DIM + 8*c))] = w0;
        w0.x = packbf(a2[0]*inv, a2[1]*inv); w0.y = packbf(a2[2]*inv, a2[3]*inv);
        w0.z = packbf(a2[4]*inv, a2[5]*inv); w0.w = packbf(a2[6]*inv, a2[7]*inv);
        Af[SW(fo(m, 2*DIM + 8*c))] = w0;
        Af[SW(fo(m, KS + 8*c))] = res;
    }
    __syncthreads();

    // ---------------- MFMA GEMM: 4 waves x 2 output tiles ----------------
    const int w    = t >> 6;                // 0..3 (wave)
    const int mm   = lane & 15;
    const int q    = lane >> 4;
    f32x4 acc0 = {0,0,0,0}, acc1 = {0,0,0,0};
    {
        const short8* Aq = (const short8*)Af;
        const short8* Bq = (const short8*)Bpack;
        #pragma unroll
        for (int kk = 0; kk < 16; kk++) {
            short8 a  = Aq[SW(kk*64 + lane)];
            short8 b0 = Bq[((w*2 + 0)*16 + kk)*64 + lane];
            short8 b1 = Bq[((w*2 + 1)*16 + kk)*64 + lane];
            acc0 = __builtin_amdgcn_mfma_f32_16x16x32_bf16(a, b0, acc0, 0, 0, 0);
            acc1 = __builtin_amdgcn_mfma_f32_16x16x32_bf16(a, b1, acc1, 0, 0, 0);
        }
    }
    __syncthreads();                        // all A reads done; reuse as H

    float* H = (float*)Af;                  // H[16][132] = 8448 B < 16 KiB
    {
        int rb = q * 4;
        #pragma unroll
        for (int nt = 0; nt < 2; nt++) {
            int d = (w*2 + nt)*16 + mm;
            float lb = linb[d];
            f32x4 a = (nt == 0) ? acc0 : acc1;
            #pragma unroll
            for (int i = 0; i < 4; i++)
                H[(rb + i)*132 + d] = a[i] + lb;
        }
    }
    __syncthreads();

    // ---------------- LayerNorm stats (16 lanes per row) ----------------
    {
        int j = t >> 4, p = t & 15;
        float s1 = 0.f, s2 = 0.f;
        const float* hr = &H[j*132 + p*8];
        #pragma unroll
        for (int i = 0; i < 8; i++) { float v = hr[i]; s1 += v; s2 += v*v; }
        #pragma unroll
        for (int off = 1; off < 16; off <<= 1) {
            s1 += __shfl_xor(s1, off);
            s2 += __shfl_xor(s2, off);
        }
        if (p == 0) {
            float mu  = s1 * (1.0f/DIM);
            float var = s2 * (1.0f/DIM) - mu*mu;
            s_mu[j] = mu;
            s_rs[j] = rsqrtf(var + LN_EPS);
        }
    }
    __syncthreads();

    // ---------------- output (fp32), 2 half-blocks x 8 rows ----------------
    {
        int d  = t & 127;
        int jb = (t >> 7) * 8;
        float g = gamma[d];
        float b = beta[d];
        #pragma unroll
        for (int jj = 0; jj < 8; jj++) {
            int j = jb + jj;
            int nn = n0 + j;
            if (nn < N) {
                float hv = H[j*132 + d];
                out[(size_t)nn*DIM + d] = g * (hv - s_mu[j]) * s_rs[j] + b;
            }
        }
    }
}

extern "C" void kernel_launch(void* const* d_in, const int* in_sizes, int n_in,
                              void* d_out, int out_size, void* d_ws, size_t ws_size,
                              hipStream_t stream)
{
    const float* x   = (const float*)d_in[0];
    const int*   ei  = (const int*)d_in[1];
    const int*   et  = (const int*)d_in[2];
    const float* rw  = (const float*)d_in[3];
    const float* lw  = (const float*)d_in[4];
    const float* lb  = (const float*)d_in[5];
    const float* lg  = (const float*)d_in[6];
    const float* lbe = (const float*)d_in[7];

    const int N    = in_sizes[0] / DIM;
    const int E    = in_sizes[2];
    const int NBIN = (N + NB - 1) / NB;            // 3125 for N=50000
    const int Ee   = (E + PPART - 1) / PPART;      // 6250

    // ws layout (~22.9 MB): ovfn | ovfb | ovf | cnt | binbuf | Bpack | xbf
    char* wp = (char*)d_ws;
    int*   ovfn = (int*)wp;               wp += 16;
    uchar* ovfb = (uchar*)wp;             wp += ((size_t)NBIN + 63) & ~(size_t)63;
    int2*  ovf  = (int2*)wp;              wp += (size_t)OVFCAP * 8;              // 32 KB
    uchar* cnt  = (uchar*)wp;             wp += ((size_t)NBIN * PPART + 63) & ~(size_t)63;
    int*  binbuf = (int*)wp;              wp += (size_t)NBIN * PW * 4;           // 9.6 MB
    unsigned short* Bpack = (unsigned short*)wp;   wp += 512 * 128 * 2;          // 128 KB
    unsigned short* xbf   = (unsigned short*)wp;   wp += (size_t)N * DIM * 2;    // 12.8 MB
    (void)ws_size;

    // stream-serial: convert (zeroes ovfn/ovfb) -> edge -> main
    int cblk = (N * (DIM/8) + 255) / 256;
    if (cblk > 2048) cblk = 2048;                  // G11: cap + grid-stride
    convert_kernel<<<cblk, 256, 0, stream>>>(x, N, NBIN, rw, lw,
                                             Bpack, xbf, ovfn, ovfb);
    edge_kernel<<<PPART, 512, (size_t)NBIN * 4, stream>>>(ei, et, E, Ee, NBIN,
                                                          cnt, binbuf, ovfn, ovfb, ovf);
    main_kernel<<<NBIN, 256, 0, stream>>>(xbf, cnt, binbuf, ovfn, ovfb, ovf, Bpack,
                                          lb, lg, lbe, (float*)d_out, N);
}

// Round 11
// 169.910 us; speedup vs baseline: 1.8046x; 1.0493x over previous
//
#include <hip/hip_runtime.h>

#define DIM    128
#define NREL   3
#define KS     (NREL*DIM)    // 384
#define NB     16            // nodes per main block; bin = dst>>4
#define LN_EPS 1e-5f
#define PPART  128           // edge partitions (blocks 0..127 of fused prep)
#define KSLOT  6             // slots per (bin,part) cell
#define PW     (PPART*KSLOT) // 768 ints per bin (9.6 MB total, proven size)
#define OVFP   64            // overflow slots per partition (exp ~3.4 used)
#define NCONV  512           // convert blocks in fused prep
#define CH     256           // main: staged edges per chunk

typedef unsigned int uint;
typedef unsigned char uchar;
typedef float f32x4 __attribute__((ext_vector_type(4)));
typedef short short8 __attribute__((ext_vector_type(8)));

__device__ __forceinline__ unsigned short f2bf(float f) {   // round-to-nearest-even
    union { float f; uint u; } c; c.f = f;
    return (unsigned short)((c.u + 0x7fffu + ((c.u >> 16) & 1u)) >> 16);
}
__device__ __forceinline__ uint packbf(float a, float b) {
    return (uint)f2bf(a) | ((uint)f2bf(b) << 16);
}
__device__ __forceinline__ float blo(uint u) {              // low bf16 -> f32
    union { uint u; float f; } c; c.u = u << 16; return c.f;
}
__device__ __forceinline__ float bhi(uint u) {              // high bf16 -> f32
    union { uint u; float f; } c; c.u = u & 0xffff0000u; return c.f;
}
// Index element i from an "int" input that may really be int64 (i64 flag)
__device__ __forceinline__ int ldidx(const int* p, size_t i, int i64) {
    return i64 ? p[2*i] : p[i];
}
// 16B-slot offset of A-frag holding A[m][k..k+7] (k%8==0), 16-row tile,
// mfma_f32_16x16x32_bf16: slot = (k>>5)*64 + ((k>>3)&3)*16 + m
__device__ __forceinline__ int fo(int m, int k) {
    return ((k >> 5) << 6) + ((((k >> 3) & 3)) << 4) + m;
}
// Bank swizzle: XOR bits>=4 into bits 0-2. Bijective; balances write banks
// while leaving the MFMA read distribution at the free 2-lanes/bank.
__device__ __forceinline__ int SW(int s) { return s ^ ((s >> 4) & 7); }

// Per-block int64 probe: int64 storage => ~half of first 256 words are zero.
__device__ __forceinline__ void block_probe(const int* __restrict__ ei, int t, int* s_i64) {
    if (t < 64) {
        int z = 0;
        #pragma unroll
        for (int i = 0; i < 4; i++) z += (ei[t*4 + i] == 0) ? 1 : 0;
        #pragma unroll
        for (int off = 1; off < 64; off <<= 1) z += __shfl_xor(z, off);
        if (t == 0) *s_i64 = (z > 64) ? 1 : 0;
    }
}

// B-pack: Wbig (fp32) -> bf16 B-fragment order, 8192 uint4.
// Wbig[k][n]: k<384 -> relation_weights[k*128+n]; k>=384 -> lin_w[n*128+(k-384)]
__device__ __forceinline__ void bpack_work(int idx, const float* __restrict__ relw,
                                           const float* __restrict__ linw,
                                           unsigned short* __restrict__ Bpack) {
    if (idx < 8192) {
        int lane = idx & 63, kk = (idx >> 6) & 15, tile = idx >> 10;
        int q = lane >> 4, n = tile * 16 + (lane & 15);
        uint vv[4];
        #pragma unroll
        for (int jp = 0; jp < 4; jp++) {
            int k0 = kk * 32 + q * 8 + jp * 2;
            float v0 = (k0     < KS) ? relw[(size_t)k0*DIM + n]
                                     : linw[(size_t)n*DIM + (k0 - KS)];
            float v1 = (k0 + 1 < KS) ? relw[(size_t)(k0+1)*DIM + n]
                                     : linw[(size_t)n*DIM + (k0 + 1 - KS)];
            vv[jp] = packbf(v0, v1);
        }
        uint4 v; v.x = vv[0]; v.y = vv[1]; v.z = vv[2]; v.w = vv[3];
        ((uint4*)Bpack)[idx] = v;
    }
}

// ---------------------------------------------------------------------------
// prep_kernel (FUSED, 2-dispatch pipeline): blocks 0..PPART-1 do edge
// binning; blocks PPART..PPART+NCONV-1 do x->bf16 + B-pack concurrently
// (all 640 blocks co-resident -> convert hides under edge entirely).
// Edge: LDS hist over NBIN bins; atomic return = rank in (bin,b) cell;
//   rank<KSLOT -> binbuf[bin*PW + b*KSLOT + rank] = tag (FINAL position).
//   rank>=KSLOT (expected ~440 edges at lambda=1.5) -> per-partition list
//   with LDS counter, flushed unconditionally -> NO global init needed.
// tag = src | (dst&15)<<20 | rel<<24   (src < 2^20)
// ---------------------------------------------------------------------------
__global__ __launch_bounds__(512)
void prep_kernel(const int* __restrict__ ei, const int* __restrict__ et,
                 const float* __restrict__ x, int E, int N, int Ee, int NBIN,
                 uchar* __restrict__ cnt, int* __restrict__ binbuf,
                 int* __restrict__ ovf_cnt, int2* __restrict__ ovf,
                 const float* __restrict__ relw, const float* __restrict__ linw,
                 unsigned short* __restrict__ Bpack, unsigned short* __restrict__ xbf)
{
    extern __shared__ int lhist[];          // NBIN ints (edge blocks only)
    __shared__ int s_i64;
    __shared__ int s_ovf;
    const int b = blockIdx.x, t = threadIdx.x;

    if (b < PPART) {
        block_probe(ei, t, &s_i64);
        if (t == 0) s_ovf = 0;
        for (int i = t; i < NBIN; i += 512) lhist[i] = 0;
        __syncthreads();
        const int i64 = s_i64;
        const int e0 = b * Ee;
        const int e1 = min(E, e0 + Ee);
        for (int e = e0 + t; e < e1; e += 512) {
            int s = ldidx(ei, (size_t)e, i64);
            int d = ldidx(ei, (size_t)E + e, i64);
            int r = ldidx(et, (size_t)e, i64);
            int bin = d >> 4;
            int tag = s | ((d & 15) << 20) | (r << 24);
            int lr = atomicAdd(&lhist[bin], 1);
            if (lr < KSLOT) {
                binbuf[bin * PW + b * KSLOT + lr] = tag;
            } else {
                int oi = atomicAdd(&s_ovf, 1);
                if (oi < OVFP) ovf[b * OVFP + oi] = make_int2(tag, bin);
            }
        }
        __syncthreads();
        for (int i = t; i < NBIN; i += 512)
            cnt[i * PPART + b] = (uchar)min(lhist[i], KSLOT);
        if (t == 0) ovf_cnt[b] = min(s_ovf, OVFP);
    } else {
        const int cb   = b - PPART;
        const int cid  = cb * 512 + t;
        const int nthr = NCONV * 512;
        const float4* x4 = (const float4*)x;
        const int items = N * (DIM / 8);    // 8 floats -> 4 packed uints
        for (int i = cid; i < items; i += nthr) {
            float4 a = x4[i*2], bb = x4[i*2 + 1];
            uint4 v;
            v.x = packbf(a.x, a.y); v.y = packbf(a.z, a.w);
            v.z = packbf(bb.x, bb.y); v.w = packbf(bb.z, bb.w);
            ((uint4*)xbf)[i] = v;
        }
        bpack_work(cid, relw, linw, Bpack);
    }
}

// ---------------------------------------------------------------------------
// main: block bb owns bin bb (nodes [bb*16, bb*16+16)). ONE packed 2-wave
// shuffle scan produces both cell offsets (low 16 bits) and overflow-list
// offsets (high 16 bits). Per <=CH-slot group: parallel slot->cell map,
// register-staged tags, 48-key (node,rel) compaction, 4-way-unrolled gather.
// Overflow: compacted-list walk with binary search over s_oef (~440 entries,
// 2 iters); only blocks with matches (~11%) run the extra FINISH_CHUNK.
// Then MFMA + LN + epilogue. LDS ~20KB -> 8 blocks/CU.
// ---------------------------------------------------------------------------
__global__ __launch_bounds__(256)
void main_kernel(const unsigned short* __restrict__ xbf,
                 const uchar* __restrict__ cnt,
                 const int* __restrict__ binbuf,
                 const int* __restrict__ ovf_cnt, const int2* __restrict__ ovf,
                 const unsigned short* __restrict__ Bpack,
                 const float* __restrict__ linb,
                 const float* __restrict__ gamma,
                 const float* __restrict__ beta,
                 float* __restrict__ out, int N)
{
    __shared__ uint4 Af[1024];              // 16 KiB: A-frags, reused as H[16][132]
    __shared__ int s_cmp[CH];               // compacted srcs, (node,rel)-segmented
    __shared__ int s_map[CH];               // slot->cell map; reused as ovf staging
    __shared__ int s_cnt[48];
    __shared__ int s_off[49];
    __shared__ int s_cur[48];
    __shared__ int s_coff[PPART + 1];       // cell offsets
    __shared__ int s_oef[PPART + 1];        // overflow-list offsets
    __shared__ int s_ws0;
    __shared__ int s_n;
    __shared__ float s_mu[NB], s_rs[NB];

    const int t  = threadIdx.x;             // 0..255
    const int bb = blockIdx.x;
    const int n0 = bb * NB;
    const int m  = t >> 4;                  // node-local 0..15
    const int c  = t & 15;                  // owns dims [8c, 8c+8)
    const int n  = n0 + m;
    const int lane = t & 63;

    const uint4* xh = (const uint4*)xbf;    // 16 uint4 per bf16 row

    float a0[8], a1[8], a2[8];
    #pragma unroll
    for (int i = 0; i < 8; i++) { a0[i] = 0.f; a1[i] = 0.f; a2[i] = 0.f; }
    int deg = 0;
    uint4 res = {0,0,0,0};
    if (n < N) res = xh[(size_t)n*16 + c];  // residual (already bf16-packed)

    // ---- packed dual scan: low16 = cell counts, high16 = ovf counts ----
    // cell sum <= 768 < 2^16 (no carry into high half); ovf sum <= 8192.
    int vsc = 0;
    if (t < PPART) vsc = (int)cnt[(size_t)bb * PPART + t] + (ovf_cnt[t] << 16);
    #pragma unroll
    for (int off = 1; off < 64; off <<= 1) {
        int u = __shfl_up(vsc, off);
        if (lane >= off) vsc += u;
    }
    if (t == 63) s_ws0 = vsc;               // wave-0 total
    __syncthreads();
    if (t < PPART) {
        int v2 = vsc + ((t >= 64) ? s_ws0 : 0);
        s_coff[t + 1] = v2 & 0xFFFF;
        s_oef[t + 1]  = ((uint)v2) >> 16;
    }
    if (t == 0) { s_coff[0] = 0; s_oef[0] = 0; }
    __syncthreads();

    // phases 3-5 shared by main loop and overflow chunk:
    // assumes: s_cnt counted, `key`/`tg` registers set for t<nc, sync done.
    #define FINISH_CHUNK(NC) { \
        const int nc_ = (NC); \
        if (t < 64) { \
            int cv_ = (t < 48) ? s_cnt[t] : 0; \
            int v_ = cv_; \
            _Pragma("unroll") \
            for (int off = 1; off < 64; off <<= 1) { \
                int u_ = __shfl_up(v_, off); \
                if (t >= off) v_ += u_; \
            } \
            if (t < 48) { s_off[t + 1] = v_; s_cur[t] = v_ - cv_; } \
            if (t == 0) s_off[0] = 0; \
        } \
        __syncthreads(); \
        if (t < nc_) { \
            int pos_ = atomicAdd(&s_cur[key], 1); \
            s_cmp[pos_] = tg & 0xFFFFF; \
        } \
        __syncthreads(); \
        deg += s_off[m*3 + 3] - s_off[m*3]; \
        { \
            int p_ = s_off[m*3 + 0], pe_ = s_off[m*3 + 1]; \
            GATH(a0) \
            p_ = s_off[m*3 + 1]; pe_ = s_off[m*3 + 2]; \
            GATH(a1) \
            p_ = s_off[m*3 + 2]; pe_ = s_off[m*3 + 3]; \
            GATH(a2) \
        } \
        __syncthreads(); }

    #define GATH(ACC) \
        for (; p_ + 3 < pe_; p_ += 4) { \
            int s0 = s_cmp[p_],   s1 = s_cmp[p_+1]; \
            int s2 = s_cmp[p_+2], s3 = s_cmp[p_+3]; \
            uint4 g0 = xh[(size_t)s0*16 + c], g1 = xh[(size_t)s1*16 + c]; \
            uint4 g2 = xh[(size_t)s2*16 + c], g3 = xh[(size_t)s3*16 + c]; \
            ACC[0] += blo(g0.x)+blo(g1.x)+blo(g2.x)+blo(g3.x); \
            ACC[1] += bhi(g0.x)+bhi(g1.x)+bhi(g2.x)+bhi(g3.x); \
            ACC[2] += blo(g0.y)+blo(g1.y)+blo(g2.y)+blo(g3.y); \
            ACC[3] += bhi(g0.y)+bhi(g1.y)+bhi(g2.y)+bhi(g3.y); \
            ACC[4] += blo(g0.z)+blo(g1.z)+blo(g2.z)+blo(g3.z); \
            ACC[5] += bhi(g0.z)+bhi(g1.z)+bhi(g2.z)+bhi(g3.z); \
            ACC[6] += blo(g0.w)+blo(g1.w)+blo(g2.w)+blo(g3.w); \
            ACC[7] += bhi(g0.w)+bhi(g1.w)+bhi(g2.w)+bhi(g3.w); \
        } \
        for (; p_ < pe_; ++p_) { \
            int s0 = s_cmp[p_]; \
            uint4 g0 = xh[(size_t)s0*16 + c]; \
            ACC[0] += blo(g0.x); ACC[1] += bhi(g0.x); \
            ACC[2] += blo(g0.y); ACC[3] += bhi(g0.y); \
            ACC[4] += blo(g0.z); ACC[5] += bhi(g0.z); \
            ACC[6] += blo(g0.w); ACC[7] += bhi(g0.w); \
        }

    // ---- slotted cells, processed in groups with total <= CH ----
    int g0 = 0;
    while (g0 < PPART) {
        const int base0 = s_coff[g0];
        int gend;
        if (s_coff[PPART] - base0 <= CH) {
            gend = PPART;                   // common case: whole bin fits
        } else {
            gend = g0;
            while (gend < PPART && s_coff[gend + 1] - base0 <= CH) ++gend;
        }
        const int nc = s_coff[gend] - base0;
        // phase 1: zero key-counts + parallel slot->cell map (1 cell/thread)
        if (t < 48) s_cnt[t] = 0;
        for (int cell = g0 + t; cell < gend; cell += 256) {
            int lo = s_coff[cell] - base0, hi = s_coff[cell + 1] - base0;
            for (int s2 = lo; s2 < hi; ++s2) s_map[s2] = cell;
        }
        __syncthreads();
        // phase 2: stage tag to register + key count
        int key = -1, tg = 0;
        if (t < nc) {
            int cell = s_map[t];
            int slot = t - (s_coff[cell] - base0);
            tg = binbuf[(size_t)bb * PW + cell * KSLOT + slot];
            key = (((tg >> 20) & 15) * 3) + ((tg >> 24) & 3);
            atomicAdd(&s_cnt[key], 1);
        }
        __syncthreads();
        FINISH_CHUNK(nc)
        g0 = gend;
    }

    // ---- overflow: compacted global list (expected ~440 entries) ----
    {
        const int Lov = s_oef[PPART];
        if (Lov > 0) {
            if (t == 0) s_n = 0;
            if (t < 48) s_cnt[t] = 0;
            __syncthreads();
            for (int j = t; j < Lov; j += 256) {
                int lo = 0, hi = PPART;     // find p: s_oef[p] <= j < s_oef[p+1]
                while (hi - lo > 1) {
                    int mid = (lo + hi) >> 1;
                    if (s_oef[mid] <= j) lo = mid; else hi = mid;
                }
                int2 o = ovf[lo * OVFP + (j - s_oef[lo])];
                if (o.y == bb) {
                    int pos = atomicAdd(&s_n, 1);
                    if (pos < CH) s_map[pos] = o.x;
                }
            }
            __syncthreads();
            const int nc0 = min(s_n, CH);
            if (nc0 > 0) {                  // uniform branch (shared s_n)
                int key = -1, tg = 0;
                if (t < nc0) {
                    tg = s_map[t];
                    key = (((tg >> 20) & 15) * 3) + ((tg >> 24) & 3);
                    atomicAdd(&s_cnt[key], 1);
                }
                __syncthreads();
                FINISH_CHUNK(nc0)
            }
        }
    }
    #undef GATH
    #undef FINISH_CHUNK

    {   // pack A-frags (messages scaled by 1/deg, plus residual)
        float inv = 1.0f / fmaxf((float)deg, 1.0f);
        uint4 w0;
        w0.x = packbf(a0[0]*inv, a0[1]*inv); w0.y = packbf(a0[2]*inv, a0[3]*inv);
        w0.z = packbf(a0[4]*inv, a0[5]*inv); w0.w = packbf(a0[6]*inv, a0[7]*inv);
        Af[SW(fo(m, 0*DIM + 8*c))] = w0;
        w0.x = packbf(a1[0]*inv, a1[1]*inv); w0.y = packbf(a1[2]*inv, a1[3]*inv);
        w0.z = packbf(a1[4]*inv, a1[5]*inv); w0.w = packbf(a1[6]*inv, a1[7]*inv);
        Af[SW(fo(m, 1*DIM + 8*c))] = w0;
        w0.x = packbf(a2[0]*inv, a2[1]*inv); w0.y = packbf(a2[2]*inv, a2[3]*inv);
        w0.z = packbf(a2[4]*inv, a2[5]*inv); w0.w = packbf(a2[6]*inv, a2[7]*inv);
        Af[SW(fo(m, 2*DIM + 8*c))] = w0;
        Af[SW(fo(m, KS + 8*c))] = res;
    }
    __syncthreads();

    // ---------------- MFMA GEMM: 4 waves x 2 output tiles ----------------
    const int w    = t >> 6;                // 0..3 (wave)
    const int mm   = lane & 15;
    const int q    = lane >> 4;
    f32x4 acc0 = {0,0,0,0}, acc1 = {0,0,0,0};
    {
        const short8* Aq = (const short8*)Af;
        const short8* Bq = (const short8*)Bpack;
        #pragma unroll
        for (int kk = 0; kk < 16; kk++) {
            short8 a  = Aq[SW(kk*64 + lane)];
            short8 b0 = Bq[((w*2 + 0)*16 + kk)*64 + lane];
            short8 b1 = Bq[((w*2 + 1)*16 + kk)*64 + lane];
            acc0 = __builtin_amdgcn_mfma_f32_16x16x32_bf16(a, b0, acc0, 0, 0, 0);
            acc1 = __builtin_amdgcn_mfma_f32_16x16x32_bf16(a, b1, acc1, 0, 0, 0);
        }
    }
    __syncthreads();                        // all A reads done; reuse as H

    float* H = (float*)Af;                  // H[16][132] = 8448 B < 16 KiB
    {
        int rb = q * 4;
        #pragma unroll
        for (int nt = 0; nt < 2; nt++) {
            int d = (w*2 + nt)*16 + mm;
            float lb = linb[d];
            f32x4 a = (nt == 0) ? acc0 : acc1;
            #pragma unroll
            for (int i = 0; i < 4; i++)
                H[(rb + i)*132 + d] = a[i] + lb;
        }
    }
    __syncthreads();

    // ---------------- LayerNorm stats (16 lanes per row) ----------------
    {
        int j = t >> 4, p = t & 15;
        float s1 = 0.f, s2 = 0.f;
        const float* hr = &H[j*132 + p*8];
        #pragma unroll
        for (int i = 0; i < 8; i++) { float v = hr[i]; s1 += v; s2 += v*v; }
        #pragma unroll
        for (int off = 1; off < 16; off <<= 1) {
            s1 += __shfl_xor(s1, off);
            s2 += __shfl_xor(s2, off);
        }
        if (p == 0) {
            float mu  = s1 * (1.0f/DIM);
            float var = s2 * (1.0f/DIM) - mu*mu;
            s_mu[j] = mu;
            s_rs[j] = rsqrtf(var + LN_EPS);
        }
    }
    __syncthreads();

    // ---------------- output (fp32), 2 half-blocks x 8 rows ----------------
    {
        int d  = t & 127;
        int jb = (t >> 7) * 8;
        float g = gamma[d];
        float b = beta[d];
        #pragma unroll
        for (int jj = 0; jj < 8; jj++) {
            int j = jb + jj;
            int nn = n0 + j;
            if (nn < N) {
                float hv = H[j*132 + d];
                out[(size_t)nn*DIM + d] = g * (hv - s_mu[j]) * s_rs[j] + b;
            }
        }
    }
}

extern "C" void kernel_launch(void* const* d_in, const int* in_sizes, int n_in,
                              void* d_out, int out_size, void* d_ws, size_t ws_size,
                              hipStream_t stream)
{
    const float* x   = (const float*)d_in[0];
    const int*   ei  = (const int*)d_in[1];
    const int*   et  = (const int*)d_in[2];
    const float* rw  = (const float*)d_in[3];
    const float* lw  = (const float*)d_in[4];
    const float* lb  = (const float*)d_in[5];
    const float* lg  = (const float*)d_in[6];
    const float* lbe = (const float*)d_in[7];

    const int N    = in_sizes[0] / DIM;
    const int E    = in_sizes[2];
    const int NBIN = (N + NB - 1) / NB;            // 3125 for N=50000
    const int Ee   = (E + PPART - 1) / PPART;      // 4688

    // ws layout (~23.0 MB): ovf_cnt[128] | ovf | cnt | binbuf | Bpack | xbf
    char* wp = (char*)d_ws;
    int*   ovf_cnt = (int*)wp;            wp += 512;
    int2*  ovf     = (int2*)wp;           wp += (size_t)PPART * OVFP * 8;        // 64 KB
    uchar* cnt     = (uchar*)wp;          wp += ((size_t)NBIN * PPART + 63) & ~(size_t)63;
    int*   binbuf  = (int*)wp;            wp += (size_t)NBIN * PW * 4;           // 9.6 MB
    unsigned short* Bpack = (unsigned short*)wp;   wp += 512 * 128 * 2;          // 128 KB
    unsigned short* xbf   = (unsigned short*)wp;   wp += (size_t)N * DIM * 2;    // 12.8 MB
    (void)ws_size;

    // 2 dispatches: fused prep (edge ∥ convert) -> main
    prep_kernel<<<PPART + NCONV, 512, (size_t)NBIN * 4, stream>>>(
        ei, et, x, E, N, Ee, NBIN, cnt, binbuf, ovf_cnt, ovf, rw, lw, Bpack, xbf);
    main_kernel<<<NBIN, 256, 0, stream>>>(xbf, cnt, binbuf, ovf_cnt, ovf, Bpack,
                                          lb, lg, lbe, (float*)d_out, N);
}

// Round 12
// 161.025 us; speedup vs baseline: 1.9042x; 1.0552x over previous
//
#include <hip/hip_runtime.h>

#define DIM    128
#define NREL   3
#define KS     (NREL*DIM)    // 384
#define NB     16            // nodes per main block; bin = dst>>4
#define LN_EPS 1e-5f
#define PPART  128           // edge partitions (blocks 0..127 of fused prep)
#define KSLOT  6             // slots per (bin,part) cell
#define PW     (PPART*KSLOT) // 768 ints per bin (9.6 MB total, proven size)
#define OVFP   64            // overflow slots per partition (exp ~3.4 used)
#define NCONV  512           // convert blocks in fused prep
#define CH     256           // main: staged edges per chunk
#define REG_E  10            // edges held in registers per edge-thread
#define NWIN   4             // scatter windows (binbuf active set ~2.4MB, L2-fits)

typedef unsigned int uint;
typedef unsigned char uchar;
typedef float f32x4 __attribute__((ext_vector_type(4)));
typedef short short8 __attribute__((ext_vector_type(8)));

__device__ __forceinline__ unsigned short f2bf(float f) {   // round-to-nearest-even
    union { float f; uint u; } c; c.f = f;
    return (unsigned short)((c.u + 0x7fffu + ((c.u >> 16) & 1u)) >> 16);
}
__device__ __forceinline__ uint packbf(float a, float b) {
    return (uint)f2bf(a) | ((uint)f2bf(b) << 16);
}
__device__ __forceinline__ float blo(uint u) {              // low bf16 -> f32
    union { uint u; float f; } c; c.u = u << 16; return c.f;
}
__device__ __forceinline__ float bhi(uint u) {              // high bf16 -> f32
    union { uint u; float f; } c; c.u = u & 0xffff0000u; return c.f;
}
// Index element i from an "int" input that may really be int64 (i64 flag)
__device__ __forceinline__ int ldidx(const int* p, size_t i, int i64) {
    return i64 ? p[2*i] : p[i];
}
// 16B-slot offset of A-frag holding A[m][k..k+7] (k%8==0), 16-row tile,
// mfma_f32_16x16x32_bf16: slot = (k>>5)*64 + ((k>>3)&3)*16 + m
__device__ __forceinline__ int fo(int m, int k) {
    return ((k >> 5) << 6) + ((((k >> 3) & 3)) << 4) + m;
}
// Bank swizzle: XOR bits>=4 into bits 0-2. Bijective; balances write banks
// while leaving the MFMA read distribution at the free 2-lanes/bank.
__device__ __forceinline__ int SW(int s) { return s ^ ((s >> 4) & 7); }

// Per-block int64 probe: int64 storage => ~half of first 256 words are zero.
__device__ __forceinline__ void block_probe(const int* __restrict__ ei, int t, int* s_i64) {
    if (t < 64) {
        int z = 0;
        #pragma unroll
        for (int i = 0; i < 4; i++) z += (ei[t*4 + i] == 0) ? 1 : 0;
        #pragma unroll
        for (int off = 1; off < 64; off <<= 1) z += __shfl_xor(z, off);
        if (t == 0) *s_i64 = (z > 64) ? 1 : 0;
    }
}

// B-pack: Wbig (fp32) -> bf16 B-fragment order, 8192 uint4.
// Wbig[k][n]: k<384 -> relation_weights[k*128+n]; k>=384 -> lin_w[n*128+(k-384)]
__device__ __forceinline__ void bpack_work(int idx, const float* __restrict__ relw,
                                           const float* __restrict__ linw,
                                           unsigned short* __restrict__ Bpack) {
    if (idx < 8192) {
        int lane = idx & 63, kk = (idx >> 6) & 15, tile = idx >> 10;
        int q = lane >> 4, n = tile * 16 + (lane & 15);
        uint vv[4];
        #pragma unroll
        for (int jp = 0; jp < 4; jp++) {
            int k0 = kk * 32 + q * 8 + jp * 2;
            float v0 = (k0     < KS) ? relw[(size_t)k0*DIM + n]
                                     : linw[(size_t)n*DIM + (k0 - KS)];
            float v1 = (k0 + 1 < KS) ? relw[(size_t)(k0+1)*DIM + n]
                                     : linw[(size_t)n*DIM + (k0 + 1 - KS)];
            vv[jp] = packbf(v0, v1);
        }
        uint4 v; v.x = vv[0]; v.y = vv[1]; v.z = vv[2]; v.w = vv[3];
        ((uint4*)Bpack)[idx] = v;
    }
}

// ---------------------------------------------------------------------------
// prep_kernel (FUSED): blocks 0..PPART-1 do edge binning; blocks
// PPART..PPART+NCONV-1 do x->bf16 + B-pack concurrently.
// Edge binning v2: LOAD-ONCE into registers (fully unrolled, compile-time
// indices -> no scratch), then NWIN predicated passes scattering only bins in
// a ~2.4MB binbuf window -> store-miss line-fills become L2 hits.
// LDS hist persists across windows (bins are range-disjoint per window).
// rank<KSLOT -> binbuf[bin*PW + b*KSLOT + rank] = tag (FINAL position).
// rank>=KSLOT -> per-partition overflow list, counter flushed unconditionally.
// tag = src | (dst&15)<<20 | rel<<24   (src < 2^20)
// ---------------------------------------------------------------------------
__global__ __launch_bounds__(512)
void prep_kernel(const int* __restrict__ ei, const int* __restrict__ et,
                 const float* __restrict__ x, int E, int N, int Ee, int NBIN,
                 uchar* __restrict__ cnt, int* __restrict__ binbuf,
                 int* __restrict__ ovf_cnt, int2* __restrict__ ovf,
                 const float* __restrict__ relw, const float* __restrict__ linw,
                 unsigned short* __restrict__ Bpack, unsigned short* __restrict__ xbf)
{
    extern __shared__ int lhist[];          // NBIN ints (edge blocks only)
    __shared__ int s_i64;
    __shared__ int s_ovf;
    const int b = blockIdx.x, t = threadIdx.x;

    if (b < PPART) {
        block_probe(ei, t, &s_i64);
        if (t == 0) s_ovf = 0;
        for (int i = t; i < NBIN; i += 512) lhist[i] = 0;
        __syncthreads();
        const int i64 = s_i64;
        const int e0 = b * Ee;
        const int e1 = min(E, e0 + Ee);

        // ---- load phase: <= REG_E edges per thread into registers ----
        int binr[REG_E], tagr[REG_E];
        int nloc = 0;
        #pragma unroll
        for (int i = 0; i < REG_E; i++) {
            binr[i] = -1; tagr[i] = 0;
            int e = e0 + t + i * 512;
            if (e < e1) {
                int s = ldidx(ei, (size_t)e, i64);
                int d = ldidx(ei, (size_t)E + e, i64);
                int r = ldidx(et, (size_t)e, i64);
                binr[i] = d >> 4;
                tagr[i] = s | ((d & 15) << 20) | (r << 24);
                nloc = i + 1;
            }
        }
        (void)nloc;

        // ---- scatter phase: NWIN bin-range windows (L2-resident each) ----
        const int WIN = (NBIN + NWIN - 1) / NWIN;
        for (int w = 0; w < NWIN; ++w) {
            const int lo = w * WIN;
            const int hi = lo + WIN;
            #pragma unroll
            for (int i = 0; i < REG_E; i++) {
                int bin = binr[i];
                if (bin >= lo && bin < hi) {
                    int lr = atomicAdd(&lhist[bin], 1);
                    if (lr < KSLOT) {
                        binbuf[bin * PW + b * KSLOT + lr] = tagr[i];
                    } else {
                        int oi = atomicAdd(&s_ovf, 1);
                        if (oi < OVFP) ovf[b * OVFP + oi] = make_int2(tagr[i], bin);
                    }
                }
            }
        }

        // residual (dead for E=600K; keeps correctness for any E)
        for (int e = e0 + t + REG_E * 512; e < e1; e += 512) {
            int s = ldidx(ei, (size_t)e, i64);
            int d = ldidx(ei, (size_t)E + e, i64);
            int r = ldidx(et, (size_t)e, i64);
            int bin = d >> 4;
            int tag = s | ((d & 15) << 20) | (r << 24);
            int lr = atomicAdd(&lhist[bin], 1);
            if (lr < KSLOT) binbuf[bin * PW + b * KSLOT + lr] = tag;
            else {
                int oi = atomicAdd(&s_ovf, 1);
                if (oi < OVFP) ovf[b * OVFP + oi] = make_int2(tag, bin);
            }
        }

        __syncthreads();
        for (int i = t; i < NBIN; i += 512)
            cnt[i * PPART + b] = (uchar)min(lhist[i], KSLOT);
        if (t == 0) ovf_cnt[b] = min(s_ovf, OVFP);
    } else {
        const int cb   = b - PPART;
        const int cid  = cb * 512 + t;
        const int nthr = NCONV * 512;
        const float4* x4 = (const float4*)x;
        const int items = N * (DIM / 8);    // 8 floats -> 4 packed uints
        for (int i = cid; i < items; i += nthr) {
            float4 a = x4[i*2], bb = x4[i*2 + 1];
            uint4 v;
            v.x = packbf(a.x, a.y); v.y = packbf(a.z, a.w);
            v.z = packbf(bb.x, bb.y); v.w = packbf(bb.z, bb.w);
            ((uint4*)xbf)[i] = v;
        }
        bpack_work(cid, relw, linw, Bpack);
    }
}

// ---------------------------------------------------------------------------
// main: block bb owns bin bb (nodes [bb*16, bb*16+16)). ONE packed 2-wave
// shuffle scan produces both cell offsets (low 16 bits) and overflow-list
// offsets (high 16 bits). Per <=CH-slot group: parallel slot->cell map,
// register-staged tags, 48-key (node,rel) compaction, 4-way-unrolled gather.
// Overflow: compacted-list walk with binary search over s_oef; only blocks
// with matches run the extra FINISH_CHUNK. Then MFMA + LN + epilogue.
// ---------------------------------------------------------------------------
__global__ __launch_bounds__(256)
void main_kernel(const unsigned short* __restrict__ xbf,
                 const uchar* __restrict__ cnt,
                 const int* __restrict__ binbuf,
                 const int* __restrict__ ovf_cnt, const int2* __restrict__ ovf,
                 const unsigned short* __restrict__ Bpack,
                 const float* __restrict__ linb,
                 const float* __restrict__ gamma,
                 const float* __restrict__ beta,
                 float* __restrict__ out, int N)
{
    __shared__ uint4 Af[1024];              // 16 KiB: A-frags, reused as H[16][132]
    __shared__ int s_cmp[CH];               // compacted srcs, (node,rel)-segmented
    __shared__ int s_map[CH];               // slot->cell map; reused as ovf staging
    __shared__ int s_cnt[48];
    __shared__ int s_off[49];
    __shared__ int s_cur[48];
    __shared__ int s_coff[PPART + 1];       // cell offsets
    __shared__ int s_oef[PPART + 1];        // overflow-list offsets
    __shared__ int s_ws0;
    __shared__ int s_n;
    __shared__ float s_mu[NB], s_rs[NB];

    const int t  = threadIdx.x;             // 0..255
    const int bb = blockIdx.x;
    const int n0 = bb * NB;
    const int m  = t >> 4;                  // node-local 0..15
    const int c  = t & 15;                  // owns dims [8c, 8c+8)
    const int n  = n0 + m;
    const int lane = t & 63;

    const uint4* xh = (const uint4*)xbf;    // 16 uint4 per bf16 row

    float a0[8], a1[8], a2[8];
    #pragma unroll
    for (int i = 0; i < 8; i++) { a0[i] = 0.f; a1[i] = 0.f; a2[i] = 0.f; }
    int deg = 0;
    uint4 res = {0,0,0,0};
    if (n < N) res = xh[(size_t)n*16 + c];  // residual (already bf16-packed)

    // ---- packed dual scan: low16 = cell counts, high16 = ovf counts ----
    int vsc = 0;
    if (t < PPART) vsc = (int)cnt[(size_t)bb * PPART + t] + (ovf_cnt[t] << 16);
    #pragma unroll
    for (int off = 1; off < 64; off <<= 1) {
        int u = __shfl_up(vsc, off);
        if (lane >= off) vsc += u;
    }
    if (t == 63) s_ws0 = vsc;               // wave-0 total
    __syncthreads();
    if (t < PPART) {
        int v2 = vsc + ((t >= 64) ? s_ws0 : 0);
        s_coff[t + 1] = v2 & 0xFFFF;
        s_oef[t + 1]  = ((uint)v2) >> 16;
    }
    if (t == 0) { s_coff[0] = 0; s_oef[0] = 0; }
    __syncthreads();

    #define FINISH_CHUNK(NC) { \
        const int nc_ = (NC); \
        if (t < 64) { \
            int cv_ = (t < 48) ? s_cnt[t] : 0; \
            int v_ = cv_; \
            _Pragma("unroll") \
            for (int off = 1; off < 64; off <<= 1) { \
                int u_ = __shfl_up(v_, off); \
                if (t >= off) v_ += u_; \
            } \
            if (t < 48) { s_off[t + 1] = v_; s_cur[t] = v_ - cv_; } \
            if (t == 0) s_off[0] = 0; \
        } \
        __syncthreads(); \
        if (t < nc_) { \
            int pos_ = atomicAdd(&s_cur[key], 1); \
            s_cmp[pos_] = tg & 0xFFFFF; \
        } \
        __syncthreads(); \
        deg += s_off[m*3 + 3] - s_off[m*3]; \
        { \
            int p_ = s_off[m*3 + 0], pe_ = s_off[m*3 + 1]; \
            GATH(a0) \
            p_ = s_off[m*3 + 1]; pe_ = s_off[m*3 + 2]; \
            GATH(a1) \
            p_ = s_off[m*3 + 2]; pe_ = s_off[m*3 + 3]; \
            GATH(a2) \
        } \
        __syncthreads(); }

    #define GATH(ACC) \
        for (; p_ + 3 < pe_; p_ += 4) { \
            int s0 = s_cmp[p_],   s1 = s_cmp[p_+1]; \
            int s2 = s_cmp[p_+2], s3 = s_cmp[p_+3]; \
            uint4 g0 = xh[(size_t)s0*16 + c], g1 = xh[(size_t)s1*16 + c]; \
            uint4 g2 = xh[(size_t)s2*16 + c], g3 = xh[(size_t)s3*16 + c]; \
            ACC[0] += blo(g0.x)+blo(g1.x)+blo(g2.x)+blo(g3.x); \
            ACC[1] += bhi(g0.x)+bhi(g1.x)+bhi(g2.x)+bhi(g3.x); \
            ACC[2] += blo(g0.y)+blo(g1.y)+blo(g2.y)+blo(g3.y); \
            ACC[3] += bhi(g0.y)+bhi(g1.y)+bhi(g2.y)+bhi(g3.y); \
            ACC[4] += blo(g0.z)+blo(g1.z)+blo(g2.z)+blo(g3.z); \
            ACC[5] += bhi(g0.z)+bhi(g1.z)+bhi(g2.z)+bhi(g3.z); \
            ACC[6] += blo(g0.w)+blo(g1.w)+blo(g2.w)+blo(g3.w); \
            ACC[7] += bhi(g0.w)+bhi(g1.w)+bhi(g2.w)+bhi(g3.w); \
        } \
        for (; p_ < pe_; ++p_) { \
            int s0 = s_cmp[p_]; \
            uint4 g0 = xh[(size_t)s0*16 + c]; \
            ACC[0] += blo(g0.x); ACC[1] += bhi(g0.x); \
            ACC[2] += blo(g0.y); ACC[3] += bhi(g0.y); \
            ACC[4] += blo(g0.z); ACC[5] += bhi(g0.z); \
            ACC[6] += blo(g0.w); ACC[7] += bhi(g0.w); \
        }

    // ---- slotted cells, processed in groups with total <= CH ----
    int g0 = 0;
    while (g0 < PPART) {
        const int base0 = s_coff[g0];
        int gend;
        if (s_coff[PPART] - base0 <= CH) {
            gend = PPART;                   // common case: whole bin fits
        } else {
            gend = g0;
            while (gend < PPART && s_coff[gend + 1] - base0 <= CH) ++gend;
        }
        const int nc = s_coff[gend] - base0;
        if (t < 48) s_cnt[t] = 0;
        for (int cell = g0 + t; cell < gend; cell += 256) {
            int lo = s_coff[cell] - base0, hi = s_coff[cell + 1] - base0;
            for (int s2 = lo; s2 < hi; ++s2) s_map[s2] = cell;
        }
        __syncthreads();
        int key = -1, tg = 0;
        if (t < nc) {
            int cell = s_map[t];
            int slot = t - (s_coff[cell] - base0);
            tg = binbuf[(size_t)bb * PW + cell * KSLOT + slot];
            key = (((tg >> 20) & 15) * 3) + ((tg >> 24) & 3);
            atomicAdd(&s_cnt[key], 1);
        }
        __syncthreads();
        FINISH_CHUNK(nc)
        g0 = gend;
    }

    // ---- overflow: compacted global list (expected ~440 entries) ----
    {
        const int Lov = s_oef[PPART];
        if (Lov > 0) {
            if (t == 0) s_n = 0;
            if (t < 48) s_cnt[t] = 0;
            __syncthreads();
            for (int j = t; j < Lov; j += 256) {
                int lo = 0, hi = PPART;     // find p: s_oef[p] <= j < s_oef[p+1]
                while (hi - lo > 1) {
                    int mid = (lo + hi) >> 1;
                    if (s_oef[mid] <= j) lo = mid; else hi = mid;
                }
                int2 o = ovf[lo * OVFP + (j - s_oef[lo])];
                if (o.y == bb) {
                    int pos = atomicAdd(&s_n, 1);
                    if (pos < CH) s_map[pos] = o.x;
                }
            }
            __syncthreads();
            const int nc0 = min(s_n, CH);
            if (nc0 > 0) {                  // uniform branch (shared s_n)
                int key = -1, tg = 0;
                if (t < nc0) {
                    tg = s_map[t];
                    key = (((tg >> 20) & 15) * 3) + ((tg >> 24) & 3);
                    atomicAdd(&s_cnt[key], 1);
                }
                __syncthreads();
                FINISH_CHUNK(nc0)
            }
        }
    }
    #undef GATH
    #undef FINISH_CHUNK

    {   // pack A-frags (messages scaled by 1/deg, plus residual)
        float inv = 1.0f / fmaxf((float)deg, 1.0f);
        uint4 w0;
        w0.x = packbf(a0[0]*inv, a0[1]*inv); w0.y = packbf(a0[2]*inv, a0[3]*inv);
        w0.z = packbf(a0[4]*inv, a0[5]*inv); w0.w = packbf(a0[6]*inv, a0[7]*inv);
        Af[SW(fo(m, 0*DIM + 8*c))] = w0;
        w0.x = packbf(a1[0]*inv, a1[1]*inv); w0.y = packbf(a1[2]*inv, a1[3]*inv);
        w0.z = packbf(a1[4]*inv, a1[5]*inv); w0.w = packbf(a1[6]*inv, a1[7]*inv);
        Af[SW(fo(m, 1*DIM + 8*c))] = w0;
        w0.x = packbf(a2[0]*inv, a2[1]*inv); w0.y = packbf(a2[2]*inv, a2[3]*inv);
        w0.z = packbf(a2[4]*inv, a2[5]*inv); w0.w = packbf(a2[6]*inv, a2[7]*inv);
        Af[SW(fo(m, 2*DIM + 8*c))] = w0;
        Af[SW(fo(m, KS + 8*c))] = res;
    }
    __syncthreads();

    // ---------------- MFMA GEMM: 4 waves x 2 output tiles ----------------
    const int w    = t >> 6;                // 0..3 (wave)
    const int mm   = lane & 15;
    const int q    = lane >> 4;
    f32x4 acc0 = {0,0,0,0}, acc1 = {0,0,0,0};
    {
        const short8* Aq = (const short8*)Af;
        const short8* Bq = (const short8*)Bpack;
        #pragma unroll
        for (int kk = 0; kk < 16; kk++) {
            short8 a  = Aq[SW(kk*64 + lane)];
            short8 b0 = Bq[((w*2 + 0)*16 + kk)*64 + lane];
            short8 b1 = Bq[((w*2 + 1)*16 + kk)*64 + lane];
            acc0 = __builtin_amdgcn_mfma_f32_16x16x32_bf16(a, b0, acc0, 0, 0, 0);
            acc1 = __builtin_amdgcn_mfma_f32_16x16x32_bf16(a, b1, acc1, 0, 0, 0);
        }
    }
    __syncthreads();                        // all A reads done; reuse as H

    float* H = (float*)Af;                  // H[16][132] = 8448 B < 16 KiB
    {
        int rb = q * 4;
        #pragma unroll
        for (int nt = 0; nt < 2; nt++) {
            int d = (w*2 + nt)*16 + mm;
            float lb = linb[d];
            f32x4 a = (nt == 0) ? acc0 : acc1;
            #pragma unroll
            for (int i = 0; i < 4; i++)
                H[(rb + i)*132 + d] = a[i] + lb;
        }
    }
    __syncthreads();

    // ---------------- LayerNorm stats (16 lanes per row) ----------------
    {
        int j = t >> 4, p = t & 15;
        float s1 = 0.f, s2 = 0.f;
        const float* hr = &H[j*132 + p*8];
        #pragma unroll
        for (int i = 0; i < 8; i++) { float v = hr[i]; s1 += v; s2 += v*v; }
        #pragma unroll
        for (int off = 1; off < 16; off <<= 1) {
            s1 += __shfl_xor(s1, off);
            s2 += __shfl_xor(s2, off);
        }
        if (p == 0) {
            float mu  = s1 * (1.0f/DIM);
            float var = s2 * (1.0f/DIM) - mu*mu;
            s_mu[j] = mu;
            s_rs[j] = rsqrtf(var + LN_EPS);
        }
    }
    __syncthreads();

    // ---------------- output (fp32), 2 half-blocks x 8 rows ----------------
    {
        int d  = t & 127;
        int jb = (t >> 7) * 8;
        float g = gamma[d];
        float b = beta[d];
        #pragma unroll
        for (int jj = 0; jj < 8; jj++) {
            int j = jb + jj;
            int nn = n0 + j;
            if (nn < N) {
                float hv = H[j*132 + d];
                out[(size_t)nn*DIM + d] = g * (hv - s_mu[j]) * s_rs[j] + b;
            }
        }
    }
}

extern "C" void kernel_launch(void* const* d_in, const int* in_sizes, int n_in,
                              void* d_out, int out_size, void* d_ws, size_t ws_size,
                              hipStream_t stream)
{
    const float* x   = (const float*)d_in[0];
    const int*   ei  = (const int*)d_in[1];
    const int*   et  = (const int*)d_in[2];
    const float* rw  = (const float*)d_in[3];
    const float* lw  = (const float*)d_in[4];
    const float* lb  = (const float*)d_in[5];
    const float* lg  = (const float*)d_in[6];
    const float* lbe = (const float*)d_in[7];

    const int N    = in_sizes[0] / DIM;
    const int E    = in_sizes[2];
    const int NBIN = (N + NB - 1) / NB;            // 3125 for N=50000
    const int Ee   = (E + PPART - 1) / PPART;      // 4688

    // ws layout (~23.0 MB): ovf_cnt[128] | ovf | cnt | binbuf | Bpack | xbf
    char* wp = (char*)d_ws;
    int*   ovf_cnt = (int*)wp;            wp += 512;
    int2*  ovf     = (int2*)wp;           wp += (size_t)PPART * OVFP * 8;        // 64 KB
    uchar* cnt     = (uchar*)wp;          wp += ((size_t)NBIN * PPART + 63) & ~(size_t)63;
    int*   binbuf  = (int*)wp;            wp += (size_t)NBIN * PW * 4;           // 9.6 MB
    unsigned short* Bpack = (unsigned short*)wp;   wp += 512 * 128 * 2;          // 128 KB
    unsigned short* xbf   = (unsigned short*)wp;   wp += (size_t)N * DIM * 2;    // 12.8 MB
    (void)ws_size;

    // 2 dispatches: fused prep (edge ∥ convert) -> main
    prep_kernel<<<PPART + NCONV, 512, (size_t)NBIN * 4, stream>>>(
        ei, et, x, E, N, Ee, NBIN, cnt, binbuf, ovf_cnt, ovf, rw, lw, Bpack, xbf);
    main_kernel<<<NBIN, 256, 0, stream>>>(xbf, cnt, binbuf, ovf_cnt, ovf, Bpack,
                                          lb, lg, lbe, (float*)d_out, N);
}